// Round 4
// baseline (433.875 us; speedup 1.0000x reference)
//
#include <hip/hip_runtime.h>
#include <hip/hip_bf16.h>

// MHA: N=2, S=2048, E=1024, H=16, Dh=64. fp32 inputs/outputs (proven by R3
// runtime detection: bf16 read gave NaN, fp32 read gave finite). Internal
// pipeline bf16 MFMA with fp32 accumulation.
// Stage 1: q/k/v projections (X @ W^T + b), 128x128-tile bf16 MFMA GEMM,
//          fp32->bf16 conversion fused into LDS staging.
//          q -> d_out scratch (dead before final proj), k [n,h,s,d],
//          v transposed [n,h,d,s] so PV is A.B^T.
// Stage 2: flash-attention, KT=64, disjoint LDS buffers, wave-private P,
//          finite -1e30 running max.
// Stage 3: output projection -> d_out as FP32 (reference output dtype).

typedef short bf16x8 __attribute__((ext_vector_type(8)));
typedef float f32x4 __attribute__((ext_vector_type(4)));

constexpr int S = 2048;
constexpr int E = 1024;
constexpr int H = 16;
constexpr int D = 64;
constexpr int M = 2 * S;  // 4096 rows total

static __device__ __forceinline__ short f2bf(float x) {
  __hip_bfloat16 h = __float2bfloat16(x);  // RNE
  return __builtin_bit_cast(short, h);
}

// Load 8 consecutive fp32 elements, round to bf16x8.
static __device__ __forceinline__ bf16x8 load8f(const float* p) {
  float4 u0 = *(const float4*)p;
  float4 u1 = *(const float4*)(p + 4);
  bf16x8 t;
  t[0] = f2bf(u0.x); t[1] = f2bf(u0.y); t[2] = f2bf(u0.z); t[3] = f2bf(u0.w);
  t[4] = f2bf(u1.x); t[5] = f2bf(u1.y); t[6] = f2bf(u1.z); t[7] = f2bf(u1.w);
  return t;
}

// ---------------------------------------------------------------------------
// GEMM: C[row,col] = sum_k A[row,k]*B[col,k] + bias[col]
// A: [M x 1024] fp32 row-major, B: [1024 x 1024] fp32 row-major (B^T form).
// MODE 0: out bf16 at [n,h,s,d]   (q,k)
// MODE 1: out bf16 at [n,h,d,s]   (v transposed)
// MODE 2: out FP32 at [row,col]   (final output)
// ---------------------------------------------------------------------------
template <int MODE>
__global__ __launch_bounds__(256) void gemm_bt(const float* __restrict__ A,
                                               const float* __restrict__ B,
                                               const float* __restrict__ bias,
                                               void* __restrict__ outp) {
  __shared__ __align__(16) short as[128 * 40];
  __shared__ __align__(16) short bs[128 * 40];
  const int tid = threadIdx.x;
  const int lane = tid & 63, wv = tid >> 6;
  const int l15 = lane & 15, quad = lane >> 4;
  const int wm = wv & 1, wn = wv >> 1;
  const int bn = blockIdx.x, bm = blockIdx.y;

  f32x4 acc[4][4] = {};
  for (int k0 = 0; k0 < E; k0 += 32) {
    __syncthreads();
#pragma unroll
    for (int c = 0; c < 2; ++c) {
      int ch = c * 256 + tid;          // 0..511
      int row = ch >> 2, cs = (ch & 3) * 8;
      *(bf16x8*)&as[row * 40 + cs] =
          load8f(&A[(size_t)(bm * 128 + row) * E + k0 + cs]);
      *(bf16x8*)&bs[row * 40 + cs] =
          load8f(&B[(size_t)(bn * 128 + row) * E + k0 + cs]);
    }
    __syncthreads();
    bf16x8 af[4], bf[4];
#pragma unroll
    for (int t = 0; t < 4; ++t) {
      af[t] = *(bf16x8*)&as[(wm * 64 + t * 16 + l15) * 40 + quad * 8];
      bf[t] = *(bf16x8*)&bs[(wn * 64 + t * 16 + l15) * 40 + quad * 8];
    }
#pragma unroll
    for (int mt = 0; mt < 4; ++mt)
#pragma unroll
      for (int nt = 0; nt < 4; ++nt)
        acc[mt][nt] = __builtin_amdgcn_mfma_f32_16x16x32_bf16(
            af[mt], bf[nt], acc[mt][nt], 0, 0, 0);
  }

#pragma unroll
  for (int mt = 0; mt < 4; ++mt)
#pragma unroll
    for (int nt = 0; nt < 4; ++nt)
#pragma unroll
      for (int r = 0; r < 4; ++r) {
        int row = bm * 128 + wm * 64 + mt * 16 + quad * 4 + r;
        int col = bn * 128 + wn * 64 + nt * 16 + l15;
        float v = acc[mt][nt][r] + bias[col];
        if (MODE == 0) {
          int n = row >> 11, s = row & 2047, h = col >> 6, d = col & 63;
          ((short*)outp)[(((size_t)(n * H + h) * S) + s) * D + d] = f2bf(v);
        } else if (MODE == 1) {
          int n = row >> 11, s = row & 2047, h = col >> 6, d = col & 63;
          ((short*)outp)[(((size_t)(n * H + h) * D) + d) * S + s] = f2bf(v);
        } else {
          ((float*)outp)[(size_t)row * E + col] = v;
        }
      }
}

// ---------------------------------------------------------------------------
// Flash attention: grid (qt=16, h=16, n=2), 256 threads (4 waves).
// Each wave owns a 32-row q strip. q,k: [n,h,s,d]; vt: [n,h,d,s]; ctx: [t,e].
// KT=64 j-tiles; ks/vs/ps fully disjoint in LDS; ps is wave-private.
// All buffers here are internal bf16.
// ---------------------------------------------------------------------------
__global__ __launch_bounds__(256) void attn_kernel(const short* __restrict__ q,
                                                   const short* __restrict__ k,
                                                   const short* __restrict__ vt,
                                                   short* __restrict__ ctx) {
  __shared__ __align__(16) short smem[64 * 72 + 64 * 72 + 4 * 32 * 72];
  short* ks = smem;                // 64 rows (j) x 64 cols (d), stride 72
  short* vs = smem + 64 * 72;     // 64 rows (d) x 64 cols (j), stride 72
  short* ps = smem + 2 * 64 * 72; // per-wave 32 x 64, stride 72

  const int tid = threadIdx.x;
  const int lane = tid & 63, wv = tid >> 6;
  const int l15 = lane & 15, quad = lane >> 4;
  const int nh = blockIdx.z * H + blockIdx.y;
  const size_t base = (size_t)nh * S * D;
  const int q0 = blockIdx.x * 128 + wv * 32;
  const int pb = wv * 32 * 72;

  bf16x8 qf[2][2];
#pragma unroll
  for (int mt = 0; mt < 2; ++mt)
#pragma unroll
    for (int kk = 0; kk < 2; ++kk)
      qf[mt][kk] = *(const bf16x8*)&q[base + (size_t)(q0 + mt * 16 + l15) * D +
                                      kk * 32 + quad * 8];

  f32x4 o[2][4] = {};
  float mrow[2][4], lrow[2][4];
#pragma unroll
  for (int mt = 0; mt < 2; ++mt)
#pragma unroll
    for (int r = 0; r < 4; ++r) {
      mrow[mt][r] = -1e30f;
      lrow[mt][r] = 0.f;
    }

  for (int j0 = 0; j0 < S; j0 += 64) {
    __syncthreads();  // prev iter's ks/vs reads done before restaging
#pragma unroll
    for (int c = 0; c < 2; ++c) {
      int ch = c * 256 + tid;                 // 0..511
      int row = ch >> 3, cs = (ch & 7) * 8;   // 64 rows x 64 cols
      *(bf16x8*)&ks[row * 72 + cs] =
          *(const bf16x8*)&k[base + (size_t)(j0 + row) * D + cs];
      *(bf16x8*)&vs[row * 72 + cs] =
          *(const bf16x8*)&vt[base + (size_t)row * S + j0 + cs];
    }
    __syncthreads();

    // QK^T: 32x64 score strip per wave
    f32x4 sc[2][4] = {};
#pragma unroll
    for (int kk = 0; kk < 2; ++kk)
#pragma unroll
      for (int nt = 0; nt < 4; ++nt) {
        bf16x8 kf = *(bf16x8*)&ks[(nt * 16 + l15) * 72 + kk * 32 + quad * 8];
#pragma unroll
        for (int mt = 0; mt < 2; ++mt)
          sc[mt][nt] = __builtin_amdgcn_mfma_f32_16x16x32_bf16(
              qf[mt][kk], kf, sc[mt][nt], 0, 0, 0);
      }

    // online softmax on the 32x64 strip (rows wave-local)
#pragma unroll
    for (int mt = 0; mt < 2; ++mt)
#pragma unroll
      for (int nt = 0; nt < 4; ++nt)
        sc[mt][nt] *= 0.125f;  // 1/sqrt(64)
#pragma unroll
    for (int mt = 0; mt < 2; ++mt)
#pragma unroll
      for (int r = 0; r < 4; ++r) {
        float mx = sc[mt][0][r];
#pragma unroll
        for (int nt = 1; nt < 4; ++nt) mx = fmaxf(mx, sc[mt][nt][r]);
#pragma unroll
        for (int dd = 1; dd < 16; dd <<= 1) mx = fmaxf(mx, __shfl_xor(mx, dd));
        float mo = mrow[mt][r];
        float mn = fmaxf(mo, mx);
        float alpha = __expf(mo - mn);  // exp(-1e30) == 0 on first iter
        float sum = 0.f;
#pragma unroll
        for (int nt = 0; nt < 4; ++nt) {
          float p = __expf(sc[mt][nt][r] - mn);
          sc[mt][nt][r] = p;
          sum += p;
        }
#pragma unroll
        for (int dd = 1; dd < 16; dd <<= 1) sum += __shfl_xor(sum, dd);
        mrow[mt][r] = mn;
        lrow[mt][r] = lrow[mt][r] * alpha + sum;
#pragma unroll
        for (int nd = 0; nd < 4; ++nd) o[mt][nd][r] *= alpha;
      }

    // write P (C-layout regs -> row-major LDS, wave-private region;
    // same-wave write->read needs no barrier, compiler emits lgkmcnt)
#pragma unroll
    for (int mt = 0; mt < 2; ++mt)
#pragma unroll
      for (int nt = 0; nt < 4; ++nt)
#pragma unroll
        for (int r = 0; r < 4; ++r)
          ps[pb + (mt * 16 + quad * 4 + r) * 72 + nt * 16 + l15] =
              f2bf(sc[mt][nt][r]);

    // PV: O += P @ V  (A = P 32x64, B = VT rows: d indexed by l15)
#pragma unroll
    for (int kk = 0; kk < 2; ++kk) {
      bf16x8 af[2];
#pragma unroll
      for (int mt = 0; mt < 2; ++mt)
        af[mt] = *(bf16x8*)&ps[pb + (mt * 16 + l15) * 72 + kk * 32 + quad * 8];
#pragma unroll
      for (int nd = 0; nd < 4; ++nd) {
        bf16x8 bfv = *(bf16x8*)&vs[(nd * 16 + l15) * 72 + kk * 32 + quad * 8];
#pragma unroll
        for (int mt = 0; mt < 2; ++mt)
          o[mt][nd] = __builtin_amdgcn_mfma_f32_16x16x32_bf16(af[mt], bfv,
                                                              o[mt][nd], 0, 0, 0);
      }
    }
  }

  // epilogue: ctx[n*S + s, h*64 + d] = O / l
#pragma unroll
  for (int mt = 0; mt < 2; ++mt)
#pragma unroll
    for (int r = 0; r < 4; ++r) {
      float inv = 1.0f / lrow[mt][r];
      int srow = q0 + mt * 16 + quad * 4 + r;
#pragma unroll
      for (int nd = 0; nd < 4; ++nd) {
        int d = nd * 16 + l15;
        ctx[((size_t)(blockIdx.z * S + srow)) * E + blockIdx.y * D + d] =
            f2bf(o[mt][nd][r] * inv);
      }
    }
}

// ---------------------------------------------------------------------------
// ctx must be staged bf16 for the final GEMM: give gemm a bf16 A path.
// Simplest: a second GEMM taking bf16 A and fp32 B.
// ---------------------------------------------------------------------------
__global__ __launch_bounds__(256) void gemm_bt_bf16A(
    const short* __restrict__ A, const float* __restrict__ B,
    const float* __restrict__ bias, float* __restrict__ outp) {
  __shared__ __align__(16) short as[128 * 40];
  __shared__ __align__(16) short bs[128 * 40];
  const int tid = threadIdx.x;
  const int lane = tid & 63, wv = tid >> 6;
  const int l15 = lane & 15, quad = lane >> 4;
  const int wm = wv & 1, wn = wv >> 1;
  const int bn = blockIdx.x, bm = blockIdx.y;

  f32x4 acc[4][4] = {};
  for (int k0 = 0; k0 < E; k0 += 32) {
    __syncthreads();
#pragma unroll
    for (int c = 0; c < 2; ++c) {
      int ch = c * 256 + tid;          // 0..511
      int row = ch >> 2, cs = (ch & 3) * 8;
      *(bf16x8*)&as[row * 40 + cs] =
          *(const bf16x8*)&A[(size_t)(bm * 128 + row) * E + k0 + cs];
      *(bf16x8*)&bs[row * 40 + cs] =
          load8f(&B[(size_t)(bn * 128 + row) * E + k0 + cs]);
    }
    __syncthreads();
    bf16x8 af[4], bf[4];
#pragma unroll
    for (int t = 0; t < 4; ++t) {
      af[t] = *(bf16x8*)&as[(wm * 64 + t * 16 + l15) * 40 + quad * 8];
      bf[t] = *(bf16x8*)&bs[(wn * 64 + t * 16 + l15) * 40 + quad * 8];
    }
#pragma unroll
    for (int mt = 0; mt < 4; ++mt)
#pragma unroll
      for (int nt = 0; nt < 4; ++nt)
        acc[mt][nt] = __builtin_amdgcn_mfma_f32_16x16x32_bf16(
            af[mt], bf[nt], acc[mt][nt], 0, 0, 0);
  }

#pragma unroll
  for (int mt = 0; mt < 4; ++mt)
#pragma unroll
    for (int nt = 0; nt < 4; ++nt)
#pragma unroll
      for (int r = 0; r < 4; ++r) {
        int row = bm * 128 + wm * 64 + mt * 16 + quad * 4 + r;
        int col = bn * 128 + wn * 64 + nt * 16 + l15;
        outp[(size_t)row * E + col] = acc[mt][nt][r] + bias[col];
      }
}

// ---------------------------------------------------------------------------
extern "C" void kernel_launch(void* const* d_in, const int* in_sizes, int n_in,
                              void* d_out, int out_size, void* d_ws,
                              size_t ws_size, hipStream_t stream) {
  const float* values  = (const float*)d_in[0];
  const float* keys    = (const float*)d_in[1];
  const float* queries = (const float*)d_in[2];
  const float* W_v = (const float*)d_in[3];
  const float* b_v = (const float*)d_in[4];
  const float* W_k = (const float*)d_in[5];
  const float* b_k = (const float*)d_in[6];
  const float* W_q = (const float*)d_in[7];
  const float* b_q = (const float*)d_in[8];
  const float* W_o = (const float*)d_in[9];
  const float* b_o = (const float*)d_in[10];

  const size_t X = (size_t)M * E;  // 4M elements
  short* qb  = (short*)d_out;      // q (bf16) parks in fp32 d_out: 8.4 MB of
                                   // 16.8 MB; dead before final proj writes
  short* kb  = (short*)d_ws;       // [n,h,s,d] bf16
  short* vtb = kb + X;             // [n,h,d,s] bf16
  short* ctx = vtb + X;            // [t,e]     bf16  (24 MB of ws total)

  dim3 gg(E / 128, M / 128);  // (8, 32)
  gemm_bt<0><<<gg, 256, 0, stream>>>(queries, W_q, b_q, qb);
  gemm_bt<0><<<gg, 256, 0, stream>>>(keys, W_k, b_k, kb);
  gemm_bt<1><<<gg, 256, 0, stream>>>(values, W_v, b_v, vtb);
  attn_kernel<<<dim3(S / 128, H, 2), 256, 0, stream>>>(qb, kb, vtb, ctx);
  gemm_bt_bf16A<<<gg, 256, 0, stream>>>(ctx, W_o, b_o, (float*)d_out);
}

// Round 5
// 336.797 us; speedup vs baseline: 1.2882x; 1.2882x over previous
//
#include <hip/hip_runtime.h>
#include <hip/hip_bf16.h>

// MHA: N=2, S=2048, E=1024, H=16, Dh=64. fp32 in/out, internal bf16 MFMA.
// R5: weights pre-cast to bf16 (1 kernel); fused QKV projection (768 blocks,
// register-prefetched staging); attention with KT=128 staging + reg prefetch
// + exp2-domain softmax (scale folded into q projection); final GEMM with
// 64x128 tiles (512 blocks). 4 dispatches total.

typedef short bf16x8 __attribute__((ext_vector_type(8)));
typedef float f32x4 __attribute__((ext_vector_type(4)));

constexpr int S = 2048;
constexpr int E = 1024;
constexpr int H = 16;
constexpr int D = 64;
constexpr int M = 2 * S;  // 4096 rows total
// 1/sqrt(Dh) * log2(e): q is pre-scaled so QK^T scores are exp2-domain.
#define QSCALE 0.18033688011112042f

static __device__ __forceinline__ short f2bf_rne(float x) {
  unsigned u = __builtin_bit_cast(unsigned, x);
  u += 0x7fff + ((u >> 16) & 1);  // RNE, finite inputs only
  return (short)(u >> 16);
}
static __device__ __forceinline__ bf16x8 cvt8(float4 a, float4 b) {
  bf16x8 t;
  t[0] = f2bf_rne(a.x); t[1] = f2bf_rne(a.y);
  t[2] = f2bf_rne(a.z); t[3] = f2bf_rne(a.w);
  t[4] = f2bf_rne(b.x); t[5] = f2bf_rne(b.y);
  t[6] = f2bf_rne(b.z); t[7] = f2bf_rne(b.w);
  return t;
}
static __device__ __forceinline__ float fast_exp2(float x) {
#if __has_builtin(__builtin_amdgcn_exp2f)
  return __builtin_amdgcn_exp2f(x);
#else
  return __expf(0.69314718055994531f * x);
#endif
}

// ---------------------------------------------------------------------------
// Weight cast: 4 x (1024x1024) fp32 -> bf16. grid (512, 4), 8 elem/thread.
// ---------------------------------------------------------------------------
__global__ __launch_bounds__(256) void cast_w(
    const float* __restrict__ w0, const float* __restrict__ w1,
    const float* __restrict__ w2, const float* __restrict__ w3,
    short* __restrict__ o0, short* __restrict__ o1,
    short* __restrict__ o2, short* __restrict__ o3) {
  const float* s; short* d;
  switch (blockIdx.y) {
    case 0: s = w0; d = o0; break;
    case 1: s = w1; d = o1; break;
    case 2: s = w2; d = o2; break;
    default: s = w3; d = o3; break;
  }
  size_t i = ((size_t)blockIdx.x * 256 + threadIdx.x) * 8;
  float4 a = *(const float4*)&s[i];
  float4 b = *(const float4*)&s[i + 4];
  *(bf16x8*)&d[i] = cvt8(a, b);
}

// ---------------------------------------------------------------------------
// Fused QKV projection: grid (8, 32, 3); z: 0=q (scaled, [n,h,s,d] -> qb),
// 1=k ([n,h,s,d] -> kb), 2=v (transposed [n,h,d,s] -> vtb).
// A fp32 (cvt fused in staging, reg-prefetched), B bf16 (pre-cast).
// ---------------------------------------------------------------------------
__global__ __launch_bounds__(256) void qkv_gemm(
    const float* __restrict__ Vin, const float* __restrict__ Kin,
    const float* __restrict__ Qin, const short* __restrict__ Wq,
    const short* __restrict__ Wk, const short* __restrict__ Wv,
    const float* __restrict__ bq, const float* __restrict__ bk,
    const float* __restrict__ bv, short* __restrict__ qb,
    short* __restrict__ kb, short* __restrict__ vtb) {
  __shared__ __align__(16) short as[128 * 40];
  __shared__ __align__(16) short bs[128 * 40];
  const int tid = threadIdx.x;
  const int lane = tid & 63, wv = tid >> 6;
  const int l15 = lane & 15, quad = lane >> 4;
  const int wm = wv & 1, wn = wv >> 1;
  const int bn = blockIdx.x, bm = blockIdx.y, z = blockIdx.z;

  const float* A = (z == 0) ? Qin : (z == 1) ? Kin : Vin;
  const short* Bw = (z == 0) ? Wq : (z == 1) ? Wk : Wv;
  const float* bias = (z == 0) ? bq : (z == 1) ? bk : bv;

  float4 pa[4];
  bf16x8 pb[2];
  auto loadAB = [&](int k0) {
#pragma unroll
    for (int c = 0; c < 2; ++c) {
      int ch = c * 256 + tid, row = ch >> 2, cs = (ch & 3) * 8;
      const float* ap = &A[(size_t)(bm * 128 + row) * E + k0 + cs];
      pa[2 * c] = *(const float4*)ap;
      pa[2 * c + 1] = *(const float4*)(ap + 4);
      pb[c] = *(const bf16x8*)&Bw[(size_t)(bn * 128 + row) * E + k0 + cs];
    }
  };

  f32x4 acc[4][4] = {};
  loadAB(0);
  for (int k0 = 0; k0 < E; k0 += 32) {
    __syncthreads();
#pragma unroll
    for (int c = 0; c < 2; ++c) {
      int ch = c * 256 + tid, row = ch >> 2, cs = (ch & 3) * 8;
      *(bf16x8*)&as[row * 40 + cs] = cvt8(pa[2 * c], pa[2 * c + 1]);
      *(bf16x8*)&bs[row * 40 + cs] = pb[c];
    }
    __syncthreads();
    if (k0 + 32 < E) loadAB(k0 + 32);  // overlaps MFMA below
    bf16x8 af[4], bf[4];
#pragma unroll
    for (int t = 0; t < 4; ++t) {
      af[t] = *(bf16x8*)&as[(wm * 64 + t * 16 + l15) * 40 + quad * 8];
      bf[t] = *(bf16x8*)&bs[(wn * 64 + t * 16 + l15) * 40 + quad * 8];
    }
#pragma unroll
    for (int mt = 0; mt < 4; ++mt)
#pragma unroll
      for (int nt = 0; nt < 4; ++nt)
        acc[mt][nt] = __builtin_amdgcn_mfma_f32_16x16x32_bf16(
            af[mt], bf[nt], acc[mt][nt], 0, 0, 0);
  }

#pragma unroll
  for (int mt = 0; mt < 4; ++mt)
#pragma unroll
    for (int nt = 0; nt < 4; ++nt)
#pragma unroll
      for (int r = 0; r < 4; ++r) {
        int row = bm * 128 + wm * 64 + mt * 16 + quad * 4 + r;
        int col = bn * 128 + wn * 64 + nt * 16 + l15;
        float v = acc[mt][nt][r] + bias[col];
        int n = row >> 11, s = row & 2047, h = col >> 6, d = col & 63;
        if (z == 0) {  // q, pre-scaled into exp2 domain
          qb[(((size_t)(n * H + h) * S) + s) * D + d] = f2bf_rne(v * QSCALE);
        } else if (z == 1) {
          kb[(((size_t)(n * H + h) * S) + s) * D + d] = f2bf_rne(v);
        } else {
          vtb[(((size_t)(n * H + h) * D) + d) * S + s] = f2bf_rne(v);
        }
      }
}

// ---------------------------------------------------------------------------
// Flash attention: grid (16, 16, 2), 256 threads (4 waves x 32 q-rows).
// KT=128 staging with register prefetch; compute in two 64-key halves.
// q pre-scaled: scores already in exp2 domain.
// ---------------------------------------------------------------------------
__global__ __launch_bounds__(256) void attn_kernel(const short* __restrict__ q,
                                                   const short* __restrict__ k,
                                                   const short* __restrict__ vt,
                                                   short* __restrict__ ctx) {
  __shared__ __align__(16) short ks[128 * 72];      // 128 keys x 64 d
  __shared__ __align__(16) short vs[64 * 136];      // 64 d x 128 keys (V^T)
  __shared__ __align__(16) short ps[4 * 32 * 72];   // per-wave P 32 x 64

  const int tid = threadIdx.x;
  const int lane = tid & 63, wv = tid >> 6;
  const int l15 = lane & 15, quad = lane >> 4;
  const int nh = blockIdx.z * H + blockIdx.y;
  const size_t base = (size_t)nh * S * D;
  const int q0 = blockIdx.x * 128 + wv * 32;
  const int pb = wv * 32 * 72;

  bf16x8 qf[2][2];
#pragma unroll
  for (int mt = 0; mt < 2; ++mt)
#pragma unroll
    for (int kk = 0; kk < 2; ++kk)
      qf[mt][kk] = *(const bf16x8*)&q[base + (size_t)(q0 + mt * 16 + l15) * D +
                                      kk * 32 + quad * 8];

  f32x4 o[2][4] = {};
  float mrow[2][4], lrow[2][4];
#pragma unroll
  for (int mt = 0; mt < 2; ++mt)
#pragma unroll
    for (int r = 0; r < 4; ++r) {
      mrow[mt][r] = -1e30f;
      lrow[mt][r] = 0.f;
    }

  bf16x8 pk[4], pv[4];
  auto loadKV = [&](int j0) {
#pragma unroll
    for (int c = 0; c < 4; ++c) {
      int ch = c * 256 + tid;
      int kr = ch >> 3, kc = (ch & 7) * 8;   // 128 x 64
      pk[c] = *(const bf16x8*)&k[base + (size_t)(j0 + kr) * D + kc];
      int vr = ch >> 4, vc = (ch & 15) * 8;  // 64 x 128
      pv[c] = *(const bf16x8*)&vt[base + (size_t)vr * S + j0 + vc];
    }
  };

  loadKV(0);
  for (int j0 = 0; j0 < S; j0 += 128) {
    __syncthreads();  // prev iter's LDS reads done
#pragma unroll
    for (int c = 0; c < 4; ++c) {
      int ch = c * 256 + tid;
      int kr = ch >> 3, kc = (ch & 7) * 8;
      *(bf16x8*)&ks[kr * 72 + kc] = pk[c];
      int vr = ch >> 4, vc = (ch & 15) * 8;
      *(bf16x8*)&vs[vr * 136 + vc] = pv[c];
    }
    __syncthreads();
    if (j0 + 128 < S) loadKV(j0 + 128);  // overlaps both halves' compute

#pragma unroll
    for (int half = 0; half < 2; ++half) {
      // QK^T: 32x64 score strip per wave (exp2 domain, pre-scaled q)
      f32x4 sc[2][4] = {};
#pragma unroll
      for (int kk = 0; kk < 2; ++kk)
#pragma unroll
        for (int nt = 0; nt < 4; ++nt) {
          bf16x8 kf = *(bf16x8*)&ks[(half * 64 + nt * 16 + l15) * 72 +
                                    kk * 32 + quad * 8];
#pragma unroll
          for (int mt = 0; mt < 2; ++mt)
            sc[mt][nt] = __builtin_amdgcn_mfma_f32_16x16x32_bf16(
                qf[mt][kk], kf, sc[mt][nt], 0, 0, 0);
        }

      // online softmax (base-2), rows wave-local
#pragma unroll
      for (int mt = 0; mt < 2; ++mt)
#pragma unroll
        for (int r = 0; r < 4; ++r) {
          float mx = sc[mt][0][r];
#pragma unroll
          for (int nt = 1; nt < 4; ++nt) mx = fmaxf(mx, sc[mt][nt][r]);
#pragma unroll
          for (int dd = 1; dd < 16; dd <<= 1)
            mx = fmaxf(mx, __shfl_xor(mx, dd));
          float mo = mrow[mt][r];
          float mn = fmaxf(mo, mx);
          float alpha = fast_exp2(mo - mn);
          float sum = 0.f;
#pragma unroll
          for (int nt = 0; nt < 4; ++nt) {
            float p0 = fast_exp2(sc[mt][nt][0 + 0] - mn);  // placeholder
            (void)p0;
            break;
          }
#pragma unroll
          for (int nt = 0; nt < 4; ++nt) {
            float p = fast_exp2(sc[mt][nt][r] - mn);
            sc[mt][nt][r] = p;
            sum += p;
          }
#pragma unroll
          for (int dd = 1; dd < 16; dd <<= 1) sum += __shfl_xor(sum, dd);
          mrow[mt][r] = mn;
          lrow[mt][r] = lrow[mt][r] * alpha + sum;
#pragma unroll
          for (int nd = 0; nd < 4; ++nd) o[mt][nd][r] *= alpha;
        }

      // P -> wave-private LDS (same-wave write->read, lgkmcnt only)
#pragma unroll
      for (int mt = 0; mt < 2; ++mt)
#pragma unroll
        for (int nt = 0; nt < 4; ++nt)
#pragma unroll
          for (int r = 0; r < 4; ++r)
            ps[pb + (mt * 16 + quad * 4 + r) * 72 + nt * 16 + l15] =
                f2bf_rne(sc[mt][nt][r]);

      // PV: O += P @ V_half
#pragma unroll
      for (int kk = 0; kk < 2; ++kk) {
        bf16x8 af[2];
#pragma unroll
        for (int mt = 0; mt < 2; ++mt)
          af[mt] =
              *(bf16x8*)&ps[pb + (mt * 16 + l15) * 72 + kk * 32 + quad * 8];
#pragma unroll
        for (int nd = 0; nd < 4; ++nd) {
          bf16x8 bfv = *(bf16x8*)&vs[(nd * 16 + l15) * 136 + half * 64 +
                                     kk * 32 + quad * 8];
#pragma unroll
          for (int mt = 0; mt < 2; ++mt)
            o[mt][nd] = __builtin_amdgcn_mfma_f32_16x16x32_bf16(
                af[mt], bfv, o[mt][nd], 0, 0, 0);
        }
      }
    }
  }

  // epilogue: ctx[n*S + s, h*64 + d] = O / l
#pragma unroll
  for (int mt = 0; mt < 2; ++mt)
#pragma unroll
    for (int r = 0; r < 4; ++r) {
      float inv = 1.0f / lrow[mt][r];
      int srow = q0 + mt * 16 + quad * 4 + r;
#pragma unroll
      for (int nd = 0; nd < 4; ++nd) {
        int d = nd * 16 + l15;
        ctx[((size_t)(blockIdx.z * S + srow)) * E + blockIdx.y * D + d] =
            f2bf_rne(o[mt][nd][r] * inv);
      }
    }
}

// ---------------------------------------------------------------------------
// Final projection: ctx(bf16) @ W_o(bf16)^T + b_o -> fp32 d_out.
// 64x128 tiles, grid (8, 64) = 512 blocks (2/CU). Register-prefetched.
// ---------------------------------------------------------------------------
__global__ __launch_bounds__(256) void out_gemm(const short* __restrict__ A,
                                                const short* __restrict__ Bw,
                                                const float* __restrict__ bias,
                                                float* __restrict__ outp) {
  __shared__ __align__(16) short as[64 * 40];
  __shared__ __align__(16) short bs[128 * 40];
  const int tid = threadIdx.x;
  const int lane = tid & 63, wv = tid >> 6;
  const int l15 = lane & 15, quad = lane >> 4;
  const int wm = wv & 1, wn = wv >> 1;
  const int bn = blockIdx.x, bm = blockIdx.y;

  bf16x8 pa, pbf[2];
  auto loadAB = [&](int k0) {
    int arow = tid >> 2, acs = (tid & 3) * 8;
    pa = *(const bf16x8*)&A[(size_t)(bm * 64 + arow) * E + k0 + acs];
#pragma unroll
    for (int c = 0; c < 2; ++c) {
      int ch = c * 256 + tid, row = ch >> 2, cs = (ch & 3) * 8;
      pbf[c] = *(const bf16x8*)&Bw[(size_t)(bn * 128 + row) * E + k0 + cs];
    }
  };

  f32x4 acc[2][4] = {};
  loadAB(0);
  for (int k0 = 0; k0 < E; k0 += 32) {
    __syncthreads();
    {
      int arow = tid >> 2, acs = (tid & 3) * 8;
      *(bf16x8*)&as[arow * 40 + acs] = pa;
#pragma unroll
      for (int c = 0; c < 2; ++c) {
        int ch = c * 256 + tid, row = ch >> 2, cs = (ch & 3) * 8;
        *(bf16x8*)&bs[row * 40 + cs] = pbf[c];
      }
    }
    __syncthreads();
    if (k0 + 32 < E) loadAB(k0 + 32);
    bf16x8 af[2], bf[4];
#pragma unroll
    for (int t = 0; t < 2; ++t)
      af[t] = *(bf16x8*)&as[(wm * 32 + t * 16 + l15) * 40 + quad * 8];
#pragma unroll
    for (int t = 0; t < 4; ++t)
      bf[t] = *(bf16x8*)&bs[(wn * 64 + t * 16 + l15) * 40 + quad * 8];
#pragma unroll
    for (int mt = 0; mt < 2; ++mt)
#pragma unroll
      for (int nt = 0; nt < 4; ++nt)
        acc[mt][nt] = __builtin_amdgcn_mfma_f32_16x16x32_bf16(
            af[mt], bf[nt], acc[mt][nt], 0, 0, 0);
  }

#pragma unroll
  for (int mt = 0; mt < 2; ++mt)
#pragma unroll
    for (int nt = 0; nt < 4; ++nt)
#pragma unroll
      for (int r = 0; r < 4; ++r) {
        int row = bm * 64 + wm * 32 + mt * 16 + quad * 4 + r;
        int col = bn * 128 + wn * 64 + nt * 16 + l15;
        outp[(size_t)row * E + col] = acc[mt][nt][r] + bias[col];
      }
}

// ---------------------------------------------------------------------------
extern "C" void kernel_launch(void* const* d_in, const int* in_sizes, int n_in,
                              void* d_out, int out_size, void* d_ws,
                              size_t ws_size, hipStream_t stream) {
  const float* values  = (const float*)d_in[0];
  const float* keys    = (const float*)d_in[1];
  const float* queries = (const float*)d_in[2];
  const float* W_v = (const float*)d_in[3];
  const float* b_v = (const float*)d_in[4];
  const float* W_k = (const float*)d_in[5];
  const float* b_k = (const float*)d_in[6];
  const float* W_q = (const float*)d_in[7];
  const float* b_q = (const float*)d_in[8];
  const float* W_o = (const float*)d_in[9];
  const float* b_o = (const float*)d_in[10];

  const size_t X = (size_t)M * E;      // 4M elements
  const size_t W = (size_t)E * E;      // 1M elements
  short* qb  = (short*)d_out;          // bf16 q parks in fp32 d_out (dead
                                       // before out_gemm overwrites)
  short* kb  = (short*)d_ws;           // [0 .. 4M)
  short* vtb = kb + X;                 // [4M .. 8M)
  short* ctx = vtb + X;                // [8M .. 12M)
  short* wqb = ctx;                    // weights park inside ctx region
  short* wkb = ctx + W;                //   (dead before attn writes ctx)
  short* wvb = ctx + 2 * W;
  short* wob = ctx + 4 * W;            // [12M .. 13M) — survives attention

  cast_w<<<dim3(W / 2048, 4), 256, 0, stream>>>(W_q, W_k, W_v, W_o, wqb, wkb,
                                                wvb, wob);
  qkv_gemm<<<dim3(E / 128, M / 128, 3), 256, 0, stream>>>(
      values, keys, queries, wqb, wkb, wvb, b_q, b_k, b_v, qb, kb, vtb);
  attn_kernel<<<dim3(S / 128, H, 2), 256, 0, stream>>>(qb, kb, vtb, ctx);
  out_gemm<<<dim3(E / 128, M / 64), 256, 0, stream>>>(ctx, wob, b_o,
                                                      (float*)d_out);
}

// Round 6
// 270.267 us; speedup vs baseline: 1.6054x; 1.2462x over previous
//
#include <hip/hip_runtime.h>
#include <hip/hip_bf16.h>

// MHA: N=2, S=2048, E=1024, H=16, Dh=64. fp32 in/out, internal bf16 MFMA.
// R6: attention restructured — S^T via swapped MFMA operands (scores per
// q-row live in ONE lane), fixed-base exp2 softmax (no max tracking, no
// in-loop cross-lane reductions, no O rescale; exact power-of-2 math),
// packed b64 P-writes. GEMM stages unchanged from R5.

typedef short bf16x8 __attribute__((ext_vector_type(8)));
typedef short bf16x4 __attribute__((ext_vector_type(4)));
typedef float f32x4 __attribute__((ext_vector_type(4)));

constexpr int S = 2048;
constexpr int E = 1024;
constexpr int H = 16;
constexpr int D = 64;
constexpr int M = 2 * S;  // 4096 rows total
// 1/sqrt(Dh) * log2(e): q is pre-scaled so QK^T scores are exp2-domain.
#define QSCALE 0.18033688011112042f

static __device__ __forceinline__ short f2bf_rne(float x) {
  unsigned u = __builtin_bit_cast(unsigned, x);
  u += 0x7fff + ((u >> 16) & 1);  // RNE, finite inputs only
  return (short)(u >> 16);
}
static __device__ __forceinline__ bf16x8 cvt8(float4 a, float4 b) {
  bf16x8 t;
  t[0] = f2bf_rne(a.x); t[1] = f2bf_rne(a.y);
  t[2] = f2bf_rne(a.z); t[3] = f2bf_rne(a.w);
  t[4] = f2bf_rne(b.x); t[5] = f2bf_rne(b.y);
  t[6] = f2bf_rne(b.z); t[7] = f2bf_rne(b.w);
  return t;
}
static __device__ __forceinline__ float fast_exp2(float x) {
#if __has_builtin(__builtin_amdgcn_exp2f)
  return __builtin_amdgcn_exp2f(x);
#else
  return __expf(0.69314718055994531f * x);
#endif
}

// ---------------------------------------------------------------------------
// Weight cast: 4 x (1024x1024) fp32 -> bf16. grid (512, 4), 8 elem/thread.
// ---------------------------------------------------------------------------
__global__ __launch_bounds__(256) void cast_w(
    const float* __restrict__ w0, const float* __restrict__ w1,
    const float* __restrict__ w2, const float* __restrict__ w3,
    short* __restrict__ o0, short* __restrict__ o1,
    short* __restrict__ o2, short* __restrict__ o3) {
  const float* s; short* d;
  switch (blockIdx.y) {
    case 0: s = w0; d = o0; break;
    case 1: s = w1; d = o1; break;
    case 2: s = w2; d = o2; break;
    default: s = w3; d = o3; break;
  }
  size_t i = ((size_t)blockIdx.x * 256 + threadIdx.x) * 8;
  float4 a = *(const float4*)&s[i];
  float4 b = *(const float4*)&s[i + 4];
  *(bf16x8*)&d[i] = cvt8(a, b);
}

// ---------------------------------------------------------------------------
// Fused QKV projection: grid (8, 32, 3); z: 0=q (scaled, [n,h,s,d] -> qb),
// 1=k ([n,h,s,d] -> kb), 2=v (transposed [n,h,d,s] -> vtb).
// A fp32 (cvt fused in staging, reg-prefetched), B bf16 (pre-cast).
// ---------------------------------------------------------------------------
__global__ __launch_bounds__(256) void qkv_gemm(
    const float* __restrict__ Vin, const float* __restrict__ Kin,
    const float* __restrict__ Qin, const short* __restrict__ Wq,
    const short* __restrict__ Wk, const short* __restrict__ Wv,
    const float* __restrict__ bq, const float* __restrict__ bk,
    const float* __restrict__ bv, short* __restrict__ qb,
    short* __restrict__ kb, short* __restrict__ vtb) {
  __shared__ __align__(16) short as[128 * 40];
  __shared__ __align__(16) short bs[128 * 40];
  const int tid = threadIdx.x;
  const int lane = tid & 63, wv = tid >> 6;
  const int l15 = lane & 15, quad = lane >> 4;
  const int wm = wv & 1, wn = wv >> 1;
  const int bn = blockIdx.x, bm = blockIdx.y, z = blockIdx.z;

  const float* A = (z == 0) ? Qin : (z == 1) ? Kin : Vin;
  const short* Bw = (z == 0) ? Wq : (z == 1) ? Wk : Wv;
  const float* bias = (z == 0) ? bq : (z == 1) ? bk : bv;

  float4 pa[4];
  bf16x8 pb[2];
  auto loadAB = [&](int k0) {
#pragma unroll
    for (int c = 0; c < 2; ++c) {
      int ch = c * 256 + tid, row = ch >> 2, cs = (ch & 3) * 8;
      const float* ap = &A[(size_t)(bm * 128 + row) * E + k0 + cs];
      pa[2 * c] = *(const float4*)ap;
      pa[2 * c + 1] = *(const float4*)(ap + 4);
      pb[c] = *(const bf16x8*)&Bw[(size_t)(bn * 128 + row) * E + k0 + cs];
    }
  };

  f32x4 acc[4][4] = {};
  loadAB(0);
  for (int k0 = 0; k0 < E; k0 += 32) {
    __syncthreads();
#pragma unroll
    for (int c = 0; c < 2; ++c) {
      int ch = c * 256 + tid, row = ch >> 2, cs = (ch & 3) * 8;
      *(bf16x8*)&as[row * 40 + cs] = cvt8(pa[2 * c], pa[2 * c + 1]);
      *(bf16x8*)&bs[row * 40 + cs] = pb[c];
    }
    __syncthreads();
    if (k0 + 32 < E) loadAB(k0 + 32);  // overlaps MFMA below
    bf16x8 af[4], bf[4];
#pragma unroll
    for (int t = 0; t < 4; ++t) {
      af[t] = *(bf16x8*)&as[(wm * 64 + t * 16 + l15) * 40 + quad * 8];
      bf[t] = *(bf16x8*)&bs[(wn * 64 + t * 16 + l15) * 40 + quad * 8];
    }
#pragma unroll
    for (int mt = 0; mt < 4; ++mt)
#pragma unroll
      for (int nt = 0; nt < 4; ++nt)
        acc[mt][nt] = __builtin_amdgcn_mfma_f32_16x16x32_bf16(
            af[mt], bf[nt], acc[mt][nt], 0, 0, 0);
  }

#pragma unroll
  for (int mt = 0; mt < 4; ++mt)
#pragma unroll
    for (int nt = 0; nt < 4; ++nt)
#pragma unroll
      for (int r = 0; r < 4; ++r) {
        int row = bm * 128 + wm * 64 + mt * 16 + quad * 4 + r;
        int col = bn * 128 + wn * 64 + nt * 16 + l15;
        float v = acc[mt][nt][r] + bias[col];
        int n = row >> 11, s = row & 2047, h = col >> 6, d = col & 63;
        if (z == 0) {  // q, pre-scaled into exp2 domain
          qb[(((size_t)(n * H + h) * S) + s) * D + d] = f2bf_rne(v * QSCALE);
        } else if (z == 1) {
          kb[(((size_t)(n * H + h) * S) + s) * D + d] = f2bf_rne(v);
        } else {
          vtb[(((size_t)(n * H + h) * D) + d) * S + s] = f2bf_rne(v);
        }
      }
}

// ---------------------------------------------------------------------------
// Flash attention R6: grid (16, 16, 2), 256 threads (4 waves x 32 q-rows).
// S^T trick: mfma(kf, qf) gives C-tile [key][qrow] -> each lane owns full
// rows of one q-row (l15). Fixed-base exp2 softmax: no max tracking (scores
// bounded; skipping max-sub is exact power-of-2 scaling), l accumulated
// per-lane, reduced once at the end. P written as packed b64 (4 consecutive
// keys of one q-row), read back as b128 A-frags for PV.
// ---------------------------------------------------------------------------
__global__ __launch_bounds__(256) void attn_kernel(const short* __restrict__ q,
                                                   const short* __restrict__ k,
                                                   const short* __restrict__ vt,
                                                   short* __restrict__ ctx) {
  __shared__ __align__(16) short ks[128 * 72];      // 128 keys x 64 d
  __shared__ __align__(16) short vs[64 * 136];      // 64 d x 128 keys (V^T)
  __shared__ __align__(16) short ps[4 * 32 * 72];   // per-wave P 32 x 64

  const int tid = threadIdx.x;
  const int lane = tid & 63, wv = tid >> 6;
  const int l15 = lane & 15, quad = lane >> 4;
  const int nh = blockIdx.z * H + blockIdx.y;
  const size_t base = (size_t)nh * S * D;
  const int q0 = blockIdx.x * 128 + wv * 32;
  const int pb = wv * 32 * 72;

  bf16x8 qf[2][2];
#pragma unroll
  for (int mt = 0; mt < 2; ++mt)
#pragma unroll
    for (int kk = 0; kk < 2; ++kk)
      qf[mt][kk] = *(const bf16x8*)&q[base + (size_t)(q0 + mt * 16 + l15) * D +
                                      kk * 32 + quad * 8];

  f32x4 o[2][4] = {};
  float lsum[2] = {0.f, 0.f};  // per-lane partial sum for q-row mt*16+l15

  bf16x8 pk[4], pv[4];
  auto loadKV = [&](int j0) {
#pragma unroll
    for (int c = 0; c < 4; ++c) {
      int ch = c * 256 + tid;
      int kr = ch >> 3, kc = (ch & 7) * 8;   // 128 x 64
      pk[c] = *(const bf16x8*)&k[base + (size_t)(j0 + kr) * D + kc];
      int vr = ch >> 4, vc = (ch & 15) * 8;  // 64 x 128
      pv[c] = *(const bf16x8*)&vt[base + (size_t)vr * S + j0 + vc];
    }
  };

  loadKV(0);
  for (int j0 = 0; j0 < S; j0 += 128) {
    __syncthreads();  // prev iter's LDS reads done
#pragma unroll
    for (int c = 0; c < 4; ++c) {
      int ch = c * 256 + tid;
      int kr = ch >> 3, kc = (ch & 7) * 8;
      *(bf16x8*)&ks[kr * 72 + kc] = pk[c];
      int vr = ch >> 4, vc = (ch & 15) * 8;
      *(bf16x8*)&vs[vr * 136 + vc] = pv[c];
    }
    __syncthreads();
    if (j0 + 128 < S) loadKV(j0 + 128);  // overlaps both halves' compute

#pragma unroll
    for (int half = 0; half < 2; ++half) {
      // S^T: tiles [key 16][qrow 16]; lane holds keys kt*16+quad*4+r for
      // q-row mt*16+l15 (exp2 domain, q pre-scaled).
      f32x4 sc[4][2] = {};
#pragma unroll
      for (int kk = 0; kk < 2; ++kk)
#pragma unroll
        for (int kt = 0; kt < 4; ++kt) {
          bf16x8 kf = *(bf16x8*)&ks[(half * 64 + kt * 16 + l15) * 72 +
                                    kk * 32 + quad * 8];
#pragma unroll
          for (int mt = 0; mt < 2; ++mt)
            sc[kt][mt] = __builtin_amdgcn_mfma_f32_16x16x32_bf16(
                kf, qf[mt][kk], sc[kt][mt], 0, 0, 0);
        }

      // fixed-base softmax: p = exp2(s); accumulate l per-lane; pack b64.
#pragma unroll
      for (int kt = 0; kt < 4; ++kt)
#pragma unroll
        for (int mt = 0; mt < 2; ++mt) {
          bf16x4 pq;
#pragma unroll
          for (int r = 0; r < 4; ++r) {
            float p = fast_exp2(sc[kt][mt][r]);
            lsum[mt] += p;
            pq[r] = f2bf_rne(p);
          }
          *(bf16x4*)&ps[pb + (mt * 16 + l15) * 72 + kt * 16 + quad * 4] = pq;
        }

      // PV: O += P @ V_half (A = P row-major from ps, B = V^T tile)
#pragma unroll
      for (int kk = 0; kk < 2; ++kk) {
        bf16x8 af[2];
#pragma unroll
        for (int mt = 0; mt < 2; ++mt)
          af[mt] =
              *(bf16x8*)&ps[pb + (mt * 16 + l15) * 72 + kk * 32 + quad * 8];
#pragma unroll
        for (int nd = 0; nd < 4; ++nd) {
          bf16x8 bfv = *(bf16x8*)&vs[(nd * 16 + l15) * 136 + half * 64 +
                                     kk * 32 + quad * 8];
#pragma unroll
          for (int mt = 0; mt < 2; ++mt)
            o[mt][nd] = __builtin_amdgcn_mfma_f32_16x16x32_bf16(
                af[mt], bfv, o[mt][nd], 0, 0, 0);
        }
      }
    }
  }

  // final l: reduce the 4 quad-copies (lanes l15, +16, +32, +48)
#pragma unroll
  for (int mt = 0; mt < 2; ++mt) {
    lsum[mt] += __shfl_xor(lsum[mt], 16);
    lsum[mt] += __shfl_xor(lsum[mt], 32);
  }

  // epilogue: O is C-layout [qrow=quad*4+r][d=l15]; fetch l for that q-row
  // from lane (quad*16 + quad... any quad holds full l after the reduce).
#pragma unroll
  for (int mt = 0; mt < 2; ++mt)
#pragma unroll
    for (int r = 0; r < 4; ++r) {
      int src = (lane & 48) + ((lane >> 4) & 3) * 4 + r;  // lane w/ l15=qrow
      float lfull = __shfl(lsum[mt], src);
      float inv = 1.0f / lfull;
      int srow = q0 + mt * 16 + quad * 4 + r;
#pragma unroll
      for (int nd = 0; nd < 4; ++nd) {
        int d = nd * 16 + l15;
        ctx[((size_t)(blockIdx.z * S + srow)) * E + blockIdx.y * D + d] =
            f2bf_rne(o[mt][nd][r] * inv);
      }
    }
}

// ---------------------------------------------------------------------------
// Final projection: ctx(bf16) @ W_o(bf16)^T + b_o -> fp32 d_out.
// 64x128 tiles, grid (8, 64) = 512 blocks (2/CU). Register-prefetched.
// ---------------------------------------------------------------------------
__global__ __launch_bounds__(256) void out_gemm(const short* __restrict__ A,
                                                const short* __restrict__ Bw,
                                                const float* __restrict__ bias,
                                                float* __restrict__ outp) {
  __shared__ __align__(16) short as[64 * 40];
  __shared__ __align__(16) short bs[128 * 40];
  const int tid = threadIdx.x;
  const int lane = tid & 63, wv = tid >> 6;
  const int l15 = lane & 15, quad = lane >> 4;
  const int wm = wv & 1, wn = wv >> 1;
  const int bn = blockIdx.x, bm = blockIdx.y;

  bf16x8 pa, pbf[2];
  auto loadAB = [&](int k0) {
    int arow = tid >> 2, acs = (tid & 3) * 8;
    pa = *(const bf16x8*)&A[(size_t)(bm * 64 + arow) * E + k0 + acs];
#pragma unroll
    for (int c = 0; c < 2; ++c) {
      int ch = c * 256 + tid, row = ch >> 2, cs = (ch & 3) * 8;
      pbf[c] = *(const bf16x8*)&Bw[(size_t)(bn * 128 + row) * E + k0 + cs];
    }
  };

  f32x4 acc[2][4] = {};
  loadAB(0);
  for (int k0 = 0; k0 < E; k0 += 32) {
    __syncthreads();
    {
      int arow = tid >> 2, acs = (tid & 3) * 8;
      *(bf16x8*)&as[arow * 40 + acs] = pa;
#pragma unroll
      for (int c = 0; c < 2; ++c) {
        int ch = c * 256 + tid, row = ch >> 2, cs = (ch & 3) * 8;
        *(bf16x8*)&bs[row * 40 + cs] = pbf[c];
      }
    }
    __syncthreads();
    if (k0 + 32 < E) loadAB(k0 + 32);
    bf16x8 af[2], bf[4];
#pragma unroll
    for (int t = 0; t < 2; ++t)
      af[t] = *(bf16x8*)&as[(wm * 32 + t * 16 + l15) * 40 + quad * 8];
#pragma unroll
    for (int t = 0; t < 4; ++t)
      bf[t] = *(bf16x8*)&bs[(wn * 64 + t * 16 + l15) * 40 + quad * 8];
#pragma unroll
    for (int mt = 0; mt < 2; ++mt)
#pragma unroll
      for (int nt = 0; nt < 4; ++nt)
        acc[mt][nt] = __builtin_amdgcn_mfma_f32_16x16x32_bf16(
            af[mt], bf[nt], acc[mt][nt], 0, 0, 0);
  }

#pragma unroll
  for (int mt = 0; mt < 2; ++mt)
#pragma unroll
    for (int nt = 0; nt < 4; ++nt)
#pragma unroll
      for (int r = 0; r < 4; ++r) {
        int row = bm * 64 + wm * 32 + mt * 16 + quad * 4 + r;
        int col = bn * 128 + wn * 64 + nt * 16 + l15;
        outp[(size_t)row * E + col] = acc[mt][nt][r] + bias[col];
      }
}

// ---------------------------------------------------------------------------
extern "C" void kernel_launch(void* const* d_in, const int* in_sizes, int n_in,
                              void* d_out, int out_size, void* d_ws,
                              size_t ws_size, hipStream_t stream) {
  const float* values  = (const float*)d_in[0];
  const float* keys    = (const float*)d_in[1];
  const float* queries = (const float*)d_in[2];
  const float* W_v = (const float*)d_in[3];
  const float* b_v = (const float*)d_in[4];
  const float* W_k = (const float*)d_in[5];
  const float* b_k = (const float*)d_in[6];
  const float* W_q = (const float*)d_in[7];
  const float* b_q = (const float*)d_in[8];
  const float* W_o = (const float*)d_in[9];
  const float* b_o = (const float*)d_in[10];

  const size_t X = (size_t)M * E;      // 4M elements
  const size_t W = (size_t)E * E;      // 1M elements
  short* qb  = (short*)d_out;          // bf16 q parks in fp32 d_out (dead
                                       // before out_gemm overwrites)
  short* kb  = (short*)d_ws;           // [0 .. 4M)
  short* vtb = kb + X;                 // [4M .. 8M)
  short* ctx = vtb + X;                // [8M .. 12M)
  short* wqb = ctx;                    // weights park inside ctx region
  short* wkb = ctx + W;                //   (dead before attn writes ctx)
  short* wvb = ctx + 2 * W;
  short* wob = ctx + 4 * W;            // [12M .. 13M) — survives attention

  cast_w<<<dim3(W / 2048, 4), 256, 0, stream>>>(W_q, W_k, W_v, W_o, wqb, wkb,
                                                wvb, wob);
  qkv_gemm<<<dim3(E / 128, M / 128, 3), 256, 0, stream>>>(
      values, keys, queries, wqb, wkb, wvb, b_q, b_k, b_v, qb, kb, vtb);
  attn_kernel<<<dim3(S / 128, H, 2), 256, 0, stream>>>(qb, kb, vtb, ctx);
  out_gemm<<<dim3(E / 128, M / 64), 256, 0, stream>>>(ctx, wob, b_o,
                                                      (float*)d_out);
}

// Round 7
// 265.021 us; speedup vs baseline: 1.6371x; 1.0198x over previous
//
#include <hip/hip_runtime.h>
#include <hip/hip_bf16.h>

// MHA: N=2, S=2048, E=1024, H=16, Dh=64. fp32 in/out, internal bf16 MFMA.
// R7: XCD-aware block swizzles (XCD presumed = bid%8) so tiles that share
// input data are processed on ONE XCD's L2: qkv A-tiles owned by a single
// XCD (kills the 8x A over-fetch, FETCH 200->~75 MB), out_gemm ctx-tiles
// likewise, attn heads pinned per-XCD (K/V L2-resident). Numerics unchanged.

typedef short bf16x8 __attribute__((ext_vector_type(8)));
typedef short bf16x4 __attribute__((ext_vector_type(4)));
typedef float f32x4 __attribute__((ext_vector_type(4)));

constexpr int S = 2048;
constexpr int E = 1024;
constexpr int H = 16;
constexpr int D = 64;
constexpr int M = 2 * S;  // 4096 rows total
// 1/sqrt(Dh) * log2(e): q is pre-scaled so QK^T scores are exp2-domain.
#define QSCALE 0.18033688011112042f

static __device__ __forceinline__ short f2bf_rne(float x) {
  unsigned u = __builtin_bit_cast(unsigned, x);
  u += 0x7fff + ((u >> 16) & 1);  // RNE, finite inputs only
  return (short)(u >> 16);
}
static __device__ __forceinline__ bf16x8 cvt8(float4 a, float4 b) {
  bf16x8 t;
  t[0] = f2bf_rne(a.x); t[1] = f2bf_rne(a.y);
  t[2] = f2bf_rne(a.z); t[3] = f2bf_rne(a.w);
  t[4] = f2bf_rne(b.x); t[5] = f2bf_rne(b.y);
  t[6] = f2bf_rne(b.z); t[7] = f2bf_rne(b.w);
  return t;
}
static __device__ __forceinline__ float fast_exp2(float x) {
#if __has_builtin(__builtin_amdgcn_exp2f)
  return __builtin_amdgcn_exp2f(x);
#else
  return __expf(0.69314718055994531f * x);
#endif
}

// ---------------------------------------------------------------------------
// Weight cast: 4 x (1024x1024) fp32 -> bf16. grid (512, 4), 8 elem/thread.
// ---------------------------------------------------------------------------
__global__ __launch_bounds__(256) void cast_w(
    const float* __restrict__ w0, const float* __restrict__ w1,
    const float* __restrict__ w2, const float* __restrict__ w3,
    short* __restrict__ o0, short* __restrict__ o1,
    short* __restrict__ o2, short* __restrict__ o3) {
  const float* s; short* d;
  switch (blockIdx.y) {
    case 0: s = w0; d = o0; break;
    case 1: s = w1; d = o1; break;
    case 2: s = w2; d = o2; break;
    default: s = w3; d = o3; break;
  }
  size_t i = ((size_t)blockIdx.x * 256 + threadIdx.x) * 8;
  float4 a = *(const float4*)&s[i];
  float4 b = *(const float4*)&s[i + 4];
  *(bf16x8*)&d[i] = cvt8(a, b);
}

// ---------------------------------------------------------------------------
// Fused QKV projection, XCD-swizzled. grid (8, 32, 3) linearized:
// c = bid%8 (XCD), r = bid/8; bn = r%8, t = c*12 + r/8 -> (z = t/32,
// bm = t%32). Each (z,bm) A-tile is owned by ONE XCD; its 8 bn-blocks
// arrive consecutively there -> A fetched once globally, reused from L2.
// z: 0=q (scaled, [n,h,s,d]), 1=k ([n,h,s,d]), 2=v (transposed [n,h,d,s]).
// ---------------------------------------------------------------------------
__global__ __launch_bounds__(256) void qkv_gemm(
    const float* __restrict__ Vin, const float* __restrict__ Kin,
    const float* __restrict__ Qin, const short* __restrict__ Wq,
    const short* __restrict__ Wk, const short* __restrict__ Wv,
    const float* __restrict__ bq, const float* __restrict__ bk,
    const float* __restrict__ bv, short* __restrict__ qb,
    short* __restrict__ kb, short* __restrict__ vtb) {
  __shared__ __align__(16) short as[128 * 40];
  __shared__ __align__(16) short bs[128 * 40];
  const int tid = threadIdx.x;
  const int lane = tid & 63, wv = tid >> 6;
  const int l15 = lane & 15, quad = lane >> 4;
  const int wm = wv & 1, wn = wv >> 1;

  const int bid =
      (blockIdx.z * gridDim.y + blockIdx.y) * gridDim.x + blockIdx.x;
  const int c = bid & 7, r = bid >> 3;
  const int bn = r & 7;
  const int t = c * 12 + (r >> 3);
  const int z = t >> 5, bm = t & 31;

  const float* A = (z == 0) ? Qin : (z == 1) ? Kin : Vin;
  const short* Bw = (z == 0) ? Wq : (z == 1) ? Wk : Wv;
  const float* bias = (z == 0) ? bq : (z == 1) ? bk : bv;

  float4 pa[4];
  bf16x8 pb[2];
  auto loadAB = [&](int k0) {
#pragma unroll
    for (int cc = 0; cc < 2; ++cc) {
      int ch = cc * 256 + tid, row = ch >> 2, cs = (ch & 3) * 8;
      const float* ap = &A[(size_t)(bm * 128 + row) * E + k0 + cs];
      pa[2 * cc] = *(const float4*)ap;
      pa[2 * cc + 1] = *(const float4*)(ap + 4);
      pb[cc] = *(const bf16x8*)&Bw[(size_t)(bn * 128 + row) * E + k0 + cs];
    }
  };

  f32x4 acc[4][4] = {};
  loadAB(0);
  for (int k0 = 0; k0 < E; k0 += 32) {
    __syncthreads();
#pragma unroll
    for (int cc = 0; cc < 2; ++cc) {
      int ch = cc * 256 + tid, row = ch >> 2, cs = (ch & 3) * 8;
      *(bf16x8*)&as[row * 40 + cs] = cvt8(pa[2 * cc], pa[2 * cc + 1]);
      *(bf16x8*)&bs[row * 40 + cs] = pb[cc];
    }
    __syncthreads();
    if (k0 + 32 < E) loadAB(k0 + 32);  // overlaps MFMA below
    bf16x8 af[4], bf[4];
#pragma unroll
    for (int tt = 0; tt < 4; ++tt) {
      af[tt] = *(bf16x8*)&as[(wm * 64 + tt * 16 + l15) * 40 + quad * 8];
      bf[tt] = *(bf16x8*)&bs[(wn * 64 + tt * 16 + l15) * 40 + quad * 8];
    }
#pragma unroll
    for (int mt = 0; mt < 4; ++mt)
#pragma unroll
      for (int nt = 0; nt < 4; ++nt)
        acc[mt][nt] = __builtin_amdgcn_mfma_f32_16x16x32_bf16(
            af[mt], bf[nt], acc[mt][nt], 0, 0, 0);
  }

#pragma unroll
  for (int mt = 0; mt < 4; ++mt)
#pragma unroll
    for (int nt = 0; nt < 4; ++nt)
#pragma unroll
      for (int rr = 0; rr < 4; ++rr) {
        int row = bm * 128 + wm * 64 + mt * 16 + quad * 4 + rr;
        int col = bn * 128 + wn * 64 + nt * 16 + l15;
        float v = acc[mt][nt][rr] + bias[col];
        int n = row >> 11, s = row & 2047, h = col >> 6, d = col & 63;
        if (z == 0) {  // q, pre-scaled into exp2 domain
          qb[(((size_t)(n * H + h) * S) + s) * D + d] = f2bf_rne(v * QSCALE);
        } else if (z == 1) {
          kb[(((size_t)(n * H + h) * S) + s) * D + d] = f2bf_rne(v);
        } else {
          vtb[(((size_t)(n * H + h) * D) + d) * S + s] = f2bf_rne(v);
        }
      }
}

// ---------------------------------------------------------------------------
// Flash attention R7: grid 512 linear blocks, XCD-swizzled:
// c = bid%8, r = bid/8; qt = r%16, hz = c*4 + r/16 (h = hz%16, n = hz/16).
// Each XCD owns 4 complete heads -> K/V (0.5 MB/head) L2-resident.
// S^T trick + fixed-base exp2 softmax + packed b64 P-writes (as R6).
// ---------------------------------------------------------------------------
__global__ __launch_bounds__(256) void attn_kernel(const short* __restrict__ q,
                                                   const short* __restrict__ k,
                                                   const short* __restrict__ vt,
                                                   short* __restrict__ ctx) {
  __shared__ __align__(16) short ks[128 * 72];      // 128 keys x 64 d
  __shared__ __align__(16) short vs[64 * 136];      // 64 d x 128 keys (V^T)
  __shared__ __align__(16) short ps[4 * 32 * 72];   // per-wave P 32 x 64

  const int tid = threadIdx.x;
  const int lane = tid & 63, wv = tid >> 6;
  const int l15 = lane & 15, quad = lane >> 4;

  const int bid = blockIdx.y * gridDim.x + blockIdx.x;  // 0..511
  const int c = bid & 7, r = bid >> 3;
  const int qt = r & 15;
  const int hz = c * 4 + (r >> 4);  // 0..31
  const int hh = hz & 15, nn = hz >> 4;

  const int nh = nn * H + hh;
  const size_t base = (size_t)nh * S * D;
  const int q0 = qt * 128 + wv * 32;
  const int pb = wv * 32 * 72;

  bf16x8 qf[2][2];
#pragma unroll
  for (int mt = 0; mt < 2; ++mt)
#pragma unroll
    for (int kk = 0; kk < 2; ++kk)
      qf[mt][kk] = *(const bf16x8*)&q[base + (size_t)(q0 + mt * 16 + l15) * D +
                                      kk * 32 + quad * 8];

  f32x4 o[2][4] = {};
  float lsum[2] = {0.f, 0.f};  // per-lane partial sum for q-row mt*16+l15

  bf16x8 pk[4], pv[4];
  auto loadKV = [&](int j0) {
#pragma unroll
    for (int cc = 0; cc < 4; ++cc) {
      int ch = cc * 256 + tid;
      int kr = ch >> 3, kc = (ch & 7) * 8;   // 128 x 64
      pk[cc] = *(const bf16x8*)&k[base + (size_t)(j0 + kr) * D + kc];
      int vr = ch >> 4, vc = (ch & 15) * 8;  // 64 x 128
      pv[cc] = *(const bf16x8*)&vt[base + (size_t)vr * S + j0 + vc];
    }
  };

  loadKV(0);
  for (int j0 = 0; j0 < S; j0 += 128) {
    __syncthreads();  // prev iter's LDS reads done
#pragma unroll
    for (int cc = 0; cc < 4; ++cc) {
      int ch = cc * 256 + tid;
      int kr = ch >> 3, kc = (ch & 7) * 8;
      *(bf16x8*)&ks[kr * 72 + kc] = pk[cc];
      int vr = ch >> 4, vc = (ch & 15) * 8;
      *(bf16x8*)&vs[vr * 136 + vc] = pv[cc];
    }
    __syncthreads();
    if (j0 + 128 < S) loadKV(j0 + 128);  // overlaps both halves' compute

#pragma unroll
    for (int half = 0; half < 2; ++half) {
      // S^T: tiles [key 16][qrow 16]; lane holds keys kt*16+quad*4+r for
      // q-row mt*16+l15 (exp2 domain, q pre-scaled).
      f32x4 sc[4][2] = {};
#pragma unroll
      for (int kk = 0; kk < 2; ++kk)
#pragma unroll
        for (int kt = 0; kt < 4; ++kt) {
          bf16x8 kf = *(bf16x8*)&ks[(half * 64 + kt * 16 + l15) * 72 +
                                    kk * 32 + quad * 8];
#pragma unroll
          for (int mt = 0; mt < 2; ++mt)
            sc[kt][mt] = __builtin_amdgcn_mfma_f32_16x16x32_bf16(
                kf, qf[mt][kk], sc[kt][mt], 0, 0, 0);
        }

      // fixed-base softmax: p = exp2(s); accumulate l per-lane; pack b64.
#pragma unroll
      for (int kt = 0; kt < 4; ++kt)
#pragma unroll
        for (int mt = 0; mt < 2; ++mt) {
          bf16x4 pq;
#pragma unroll
          for (int rr = 0; rr < 4; ++rr) {
            float p = fast_exp2(sc[kt][mt][rr]);
            lsum[mt] += p;
            pq[rr] = f2bf_rne(p);
          }
          *(bf16x4*)&ps[pb + (mt * 16 + l15) * 72 + kt * 16 + quad * 4] = pq;
        }

      // PV: O += P @ V_half (A = P row-major from ps, B = V^T tile)
#pragma unroll
      for (int kk = 0; kk < 2; ++kk) {
        bf16x8 af[2];
#pragma unroll
        for (int mt = 0; mt < 2; ++mt)
          af[mt] =
              *(bf16x8*)&ps[pb + (mt * 16 + l15) * 72 + kk * 32 + quad * 8];
#pragma unroll
        for (int nd = 0; nd < 4; ++nd) {
          bf16x8 bfv = *(bf16x8*)&vs[(nd * 16 + l15) * 136 + half * 64 +
                                     kk * 32 + quad * 8];
#pragma unroll
          for (int mt = 0; mt < 2; ++mt)
            o[mt][nd] = __builtin_amdgcn_mfma_f32_16x16x32_bf16(
                af[mt], bfv, o[mt][nd], 0, 0, 0);
        }
      }
    }
  }

  // final l: reduce the 4 quad-copies (lanes l15, +16, +32, +48)
#pragma unroll
  for (int mt = 0; mt < 2; ++mt) {
    lsum[mt] += __shfl_xor(lsum[mt], 16);
    lsum[mt] += __shfl_xor(lsum[mt], 32);
  }

  // epilogue: O is C-layout [qrow=quad*4+r][d=l15]; fetch l for that q-row.
#pragma unroll
  for (int mt = 0; mt < 2; ++mt)
#pragma unroll
    for (int rr = 0; rr < 4; ++rr) {
      int src = (lane & 48) + ((lane >> 4) & 3) * 4 + rr;  // lane w/ l15=qrow
      float lfull = __shfl(lsum[mt], src);
      float inv = 1.0f / lfull;
      int srow = q0 + mt * 16 + quad * 4 + rr;
#pragma unroll
      for (int nd = 0; nd < 4; ++nd) {
        int d = nd * 16 + l15;
        ctx[((size_t)(nn * S + srow)) * E + hh * D + d] =
            f2bf_rne(o[mt][nd][rr] * inv);
      }
    }
}

// ---------------------------------------------------------------------------
// Final projection: ctx(bf16) @ W_o(bf16)^T + b_o -> fp32 d_out.
// 64x128 tiles, 512 blocks, XCD-swizzled: c = bid%8, r = bid/8;
// bn = r%8, bm = c*8 + r/8 -> each ctx-tile owned by one XCD.
// ---------------------------------------------------------------------------
__global__ __launch_bounds__(256) void out_gemm(const short* __restrict__ A,
                                                const short* __restrict__ Bw,
                                                const float* __restrict__ bias,
                                                float* __restrict__ outp) {
  __shared__ __align__(16) short as[64 * 40];
  __shared__ __align__(16) short bs[128 * 40];
  const int tid = threadIdx.x;
  const int lane = tid & 63, wv = tid >> 6;
  const int l15 = lane & 15, quad = lane >> 4;
  const int wm = wv & 1, wn = wv >> 1;

  const int bid = blockIdx.y * gridDim.x + blockIdx.x;  // 0..511
  const int c = bid & 7, r = bid >> 3;
  const int bn = r & 7;
  const int bm = c * 8 + (r >> 3);  // 0..63

  bf16x8 pa, pbf[2];
  auto loadAB = [&](int k0) {
    int arow = tid >> 2, acs = (tid & 3) * 8;
    pa = *(const bf16x8*)&A[(size_t)(bm * 64 + arow) * E + k0 + acs];
#pragma unroll
    for (int cc = 0; cc < 2; ++cc) {
      int ch = cc * 256 + tid, row = ch >> 2, cs = (ch & 3) * 8;
      pbf[cc] = *(const bf16x8*)&Bw[(size_t)(bn * 128 + row) * E + k0 + cs];
    }
  };

  f32x4 acc[2][4] = {};
  loadAB(0);
  for (int k0 = 0; k0 < E; k0 += 32) {
    __syncthreads();
    {
      int arow = tid >> 2, acs = (tid & 3) * 8;
      *(bf16x8*)&as[arow * 40 + acs] = pa;
#pragma unroll
      for (int cc = 0; cc < 2; ++cc) {
        int ch = cc * 256 + tid, row = ch >> 2, cs = (ch & 3) * 8;
        *(bf16x8*)&bs[row * 40 + cs] = pbf[cc];
      }
    }
    __syncthreads();
    if (k0 + 32 < E) loadAB(k0 + 32);
    bf16x8 af[2], bf[4];
#pragma unroll
    for (int tt = 0; tt < 2; ++tt)
      af[tt] = *(bf16x8*)&as[(wm * 32 + tt * 16 + l15) * 40 + quad * 8];
#pragma unroll
    for (int tt = 0; tt < 4; ++tt)
      bf[tt] = *(bf16x8*)&bs[(wn * 64 + tt * 16 + l15) * 40 + quad * 8];
#pragma unroll
    for (int mt = 0; mt < 2; ++mt)
#pragma unroll
      for (int nt = 0; nt < 4; ++nt)
        acc[mt][nt] = __builtin_amdgcn_mfma_f32_16x16x32_bf16(
            af[mt], bf[nt], acc[mt][nt], 0, 0, 0);
  }

#pragma unroll
  for (int mt = 0; mt < 2; ++mt)
#pragma unroll
    for (int nt = 0; nt < 4; ++nt)
#pragma unroll
      for (int rr = 0; rr < 4; ++rr) {
        int row = bm * 64 + wm * 32 + mt * 16 + quad * 4 + rr;
        int col = bn * 128 + wn * 64 + nt * 16 + l15;
        outp[(size_t)row * E + col] = acc[mt][nt][rr] + bias[col];
      }
}

// ---------------------------------------------------------------------------
extern "C" void kernel_launch(void* const* d_in, const int* in_sizes, int n_in,
                              void* d_out, int out_size, void* d_ws,
                              size_t ws_size, hipStream_t stream) {
  const float* values  = (const float*)d_in[0];
  const float* keys    = (const float*)d_in[1];
  const float* queries = (const float*)d_in[2];
  const float* W_v = (const float*)d_in[3];
  const float* b_v = (const float*)d_in[4];
  const float* W_k = (const float*)d_in[5];
  const float* b_k = (const float*)d_in[6];
  const float* W_q = (const float*)d_in[7];
  const float* b_q = (const float*)d_in[8];
  const float* W_o = (const float*)d_in[9];
  const float* b_o = (const float*)d_in[10];

  const size_t X = (size_t)M * E;      // 4M elements
  const size_t W = (size_t)E * E;      // 1M elements
  short* qb  = (short*)d_out;          // bf16 q parks in fp32 d_out (dead
                                       // before out_gemm overwrites)
  short* kb  = (short*)d_ws;           // [0 .. 4M)
  short* vtb = kb + X;                 // [4M .. 8M)
  short* ctx = vtb + X;                // [8M .. 12M)
  short* wqb = ctx;                    // weights park inside ctx region
  short* wkb = ctx + W;                //   (dead before attn writes ctx)
  short* wvb = ctx + 2 * W;
  short* wob = ctx + 4 * W;            // [12M .. 13M) — survives attention

  cast_w<<<dim3(W / 2048, 4), 256, 0, stream>>>(W_q, W_k, W_v, W_o, wqb, wkb,
                                                wvb, wob);
  qkv_gemm<<<dim3(8, 32, 3), 256, 0, stream>>>(
      values, keys, queries, wqb, wkb, wvb, b_q, b_k, b_v, qb, kb, vtb);
  attn_kernel<<<dim3(16, 32), 256, 0, stream>>>(qb, kb, vtb, ctx);
  out_gemm<<<dim3(8, 64), 256, 0, stream>>>(ctx, wob, b_o, (float*)d_out);
}

// Round 8
// 237.578 us; speedup vs baseline: 1.8262x; 1.1155x over previous
//
#include <hip/hip_runtime.h>
#include <hip/hip_bf16.h>

// MHA: N=2, S=2048, E=1024, H=16, Dh=64. fp32 in/out, internal bf16 MFMA.
// R8: all GEMMs rebuilt on the m97 structure — inputs/weights pre-cast to
// bf16, global_load_lds width-16 staging (no VGPR roundtrip, no cvt in hot
// loop), XOR-swizzled LDS tiles (2-way conflicts instead of 8-way), XCD
// swizzles kept. Attention unchanged from R7. ws kept at 32 MB by
// sequentially reusing one cast buffer (kbf -> vbf -> ctx).

typedef short bf16x8 __attribute__((ext_vector_type(8)));
typedef short bf16x4 __attribute__((ext_vector_type(4)));
typedef float f32x4 __attribute__((ext_vector_type(4)));

constexpr int S = 2048;
constexpr int E = 1024;
constexpr int H = 16;
constexpr int D = 64;
constexpr int M = 2 * S;  // 4096 rows total
// 1/sqrt(Dh) * log2(e): q is pre-scaled so QK^T scores are exp2-domain.
#define QSCALE 0.18033688011112042f

static __device__ __forceinline__ short f2bf_rne(float x) {
  unsigned u = __builtin_bit_cast(unsigned, x);
  u += 0x7fff + ((u >> 16) & 1);  // RNE, finite inputs only
  return (short)(u >> 16);
}
static __device__ __forceinline__ bf16x8 cvt8(float4 a, float4 b) {
  bf16x8 t;
  t[0] = f2bf_rne(a.x); t[1] = f2bf_rne(a.y);
  t[2] = f2bf_rne(a.z); t[3] = f2bf_rne(a.w);
  t[4] = f2bf_rne(b.x); t[5] = f2bf_rne(b.y);
  t[6] = f2bf_rne(b.z); t[7] = f2bf_rne(b.w);
  return t;
}
static __device__ __forceinline__ float fast_exp2(float x) {
#if __has_builtin(__builtin_amdgcn_exp2f)
  return __builtin_amdgcn_exp2f(x);
#else
  return __expf(0.69314718055994531f * x);
#endif
}

// Async global->LDS, 16 B per lane. lds base must be wave-uniform; lane i's
// 16 B lands at lds + i*16. Global address is per-lane.
static __device__ __forceinline__ void gl_lds16(const short* g, short* l) {
  __builtin_amdgcn_global_load_lds(
      (const __attribute__((address_space(1))) void*)g,
      (__attribute__((address_space(3))) void*)l, 16, 0, 0);
}

// ---------------------------------------------------------------------------
// XOR-swizzled tile layout for [rows x 32] bf16 tiles (64 B/row).
// Physical LDS = pairs of rows (128 B = 8 chunks of 16 B). Within pair p,
// logical chunk l lives at physical chunk k = l ^ (p&7). Logical chunk l of
// pair p = row 2p + (l>>2), cols (l&3)*8 .. +7. Store side realizes the
// swizzle via the per-lane GLOBAL address; read side computes the physical
// offset. ds_read_b128 frag reads then hit each 4-bank group with exactly
// 2 lanes -> conflict-free (m136).
// Store mapping for segment s (1 KB, 8 pairs), lane i:
//   p = s*8 + i/8; k = i%8; l = k ^ (p&7); row = 2p + (l>>2); col = (l&3)*8
// Read mapping for logical (row r, chunk c in 0..3):
//   p = r>>1; l = (r&1)*4 + c; k = l ^ (p&7); shortOff = p*64 + k*8
// ---------------------------------------------------------------------------

// ---------------------------------------------------------------------------
// cast_a: queries->qbf, keys->kbf, 4 weights -> bf16. grid (2048, 6).
// ---------------------------------------------------------------------------
__global__ __launch_bounds__(256) void cast_a(
    const float* __restrict__ qs, const float* __restrict__ ks,
    const float* __restrict__ wq, const float* __restrict__ wk,
    const float* __restrict__ wv, const float* __restrict__ wo,
    short* __restrict__ qbf, short* __restrict__ kbf, short* __restrict__ wqb,
    short* __restrict__ wkb, short* __restrict__ wvb, short* __restrict__ wob) {
  const float* s;
  short* d;
  switch (blockIdx.y) {
    case 0: s = qs; d = qbf; break;
    case 1: s = ks; d = kbf; break;
    case 2: if (blockIdx.x >= 512) return; s = wq; d = wqb; break;
    case 3: if (blockIdx.x >= 512) return; s = wk; d = wkb; break;
    case 4: if (blockIdx.x >= 512) return; s = wv; d = wvb; break;
    default: if (blockIdx.x >= 512) return; s = wo; d = wob; break;
  }
  size_t i = ((size_t)blockIdx.x * 256 + threadIdx.x) * 8;
  *(bf16x8*)&d[i] = cvt8(*(const float4*)&s[i], *(const float4*)&s[i + 4]);
}

__global__ __launch_bounds__(256) void cast_one(const float* __restrict__ s,
                                                short* __restrict__ d) {
  size_t i = ((size_t)blockIdx.x * 256 + threadIdx.x) * 8;
  *(bf16x8*)&d[i] = cvt8(*(const float4*)&s[i], *(const float4*)&s[i + 4]);
}

// ---------------------------------------------------------------------------
// qk_gemm: fused q & k projections, 128x128 tiles, 512 blocks.
// XCD swizzle: c=b&7, r=b>>3; bn=r&7; t=c*8+(r>>3); z=t>>5; bm=t&31.
// A-tile (z,bm) owned by one XCD (8 bn-blocks reuse it from L2).
// ---------------------------------------------------------------------------
__global__ __launch_bounds__(256) void qk_gemm(
    const short* __restrict__ qbf, const short* __restrict__ kbf,
    const short* __restrict__ wqb, const short* __restrict__ wkb,
    const float* __restrict__ bq, const float* __restrict__ bk,
    short* __restrict__ qb, short* __restrict__ kb) {
  __shared__ __align__(16) short as[128 * 32];
  __shared__ __align__(16) short bs[128 * 32];
  const int tid = threadIdx.x;
  const int lane = tid & 63, w = tid >> 6;
  const int l15 = lane & 15, quad = lane >> 4;
  const int wm = w & 1, wn = w >> 1;

  const int b = blockIdx.x;
  const int c = b & 7, r = b >> 3;
  const int bn = r & 7;
  const int t = c * 8 + (r >> 3);
  const int z = t >> 5, bm = t & 31;

  const short* A = z ? kbf : qbf;
  const short* Bw = z ? wkb : wqb;
  const float* bias = z ? bk : bq;

  // store-side swizzled mapping for this lane, segments cc=0,1 per wave
  const short* agp[2];
  const short* bgp[2];
  int ldsb[2];
#pragma unroll
  for (int cc = 0; cc < 2; ++cc) {
    int seg = w * 2 + cc;
    int p = seg * 8 + (lane >> 3), kc = lane & 7;
    int l = kc ^ (p & 7);
    int row = 2 * p + (l >> 2), col = (l & 3) * 8;
    ldsb[cc] = seg * 512;
    agp[cc] = &A[(size_t)(bm * 128 + row) * E + col];
    bgp[cc] = &Bw[(size_t)(bn * 128 + row) * E + col];
  }

  f32x4 acc[4][4] = {};
  for (int k0 = 0; k0 < E; k0 += 32) {
    __syncthreads();  // prev frag reads done; LDS free
#pragma unroll
    for (int cc = 0; cc < 2; ++cc) {
      gl_lds16(agp[cc] + k0, &as[ldsb[cc]]);
      gl_lds16(bgp[cc] + k0, &bs[ldsb[cc]]);
    }
    __syncthreads();  // vmcnt drained by compiler before barrier -> tile ready

    bf16x8 af[4], bf[4];
#pragma unroll
    for (int tt = 0; tt < 4; ++tt) {
      int ra = wm * 64 + tt * 16 + l15;
      int pa2 = ra >> 1, la = (ra & 1) * 4 + quad, ka = la ^ (pa2 & 7);
      af[tt] = *(bf16x8*)&as[pa2 * 64 + ka * 8];
      int rb = wn * 64 + tt * 16 + l15;
      int pb2 = rb >> 1, lb = (rb & 1) * 4 + quad, kb2 = lb ^ (pb2 & 7);
      bf[tt] = *(bf16x8*)&bs[pb2 * 64 + kb2 * 8];
    }
#pragma unroll
    for (int mt = 0; mt < 4; ++mt)
#pragma unroll
      for (int nt = 0; nt < 4; ++nt)
        acc[mt][nt] = __builtin_amdgcn_mfma_f32_16x16x32_bf16(
            af[mt], bf[nt], acc[mt][nt], 0, 0, 0);
  }

#pragma unroll
  for (int mt = 0; mt < 4; ++mt)
#pragma unroll
    for (int nt = 0; nt < 4; ++nt)
#pragma unroll
      for (int rr = 0; rr < 4; ++rr) {
        int row = bm * 128 + wm * 64 + mt * 16 + quad * 4 + rr;
        int col = bn * 128 + wn * 64 + nt * 16 + l15;
        float v = acc[mt][nt][rr] + bias[col];
        int n = row >> 11, s = row & 2047, h = col >> 6, d = col & 63;
        if (z == 0) {  // q, pre-scaled into exp2 domain
          qb[(((size_t)(n * H + h) * S) + s) * D + d] = f2bf_rne(v * QSCALE);
        } else {
          kb[(((size_t)(n * H + h) * S) + s) * D + d] = f2bf_rne(v);
        }
      }
}

// ---------------------------------------------------------------------------
// 64x128-tile GEMM core, 512 blocks, XCD swizzle: bn=r&7, bm=c*8+(r>>3).
// MODE 0: v-projection -> vtb transposed [n,h,d,s] (bf16)
// MODE 1: out projection -> fp32 row-major + bias
// ---------------------------------------------------------------------------
template <int MODE>
__global__ __launch_bounds__(256) void gemm64(const short* __restrict__ A,
                                              const short* __restrict__ Bw,
                                              const float* __restrict__ bias,
                                              void* __restrict__ outp) {
  __shared__ __align__(16) short as[64 * 32];
  __shared__ __align__(16) short bs[128 * 32];
  const int tid = threadIdx.x;
  const int lane = tid & 63, w = tid >> 6;
  const int l15 = lane & 15, quad = lane >> 4;
  const int wm = w & 1, wn = w >> 1;

  const int b = blockIdx.x;
  const int c = b & 7, r = b >> 3;
  const int bn = r & 7;
  const int bm = c * 8 + (r >> 3);  // 0..63

  // A: one segment per wave (4 KB total); B: two segments per wave.
  const short* agp;
  int aldsb;
  {
    int seg = w;
    int p = seg * 8 + (lane >> 3), kc = lane & 7;
    int l = kc ^ (p & 7);
    int row = 2 * p + (l >> 2), col = (l & 3) * 8;
    aldsb = seg * 512;
    agp = &A[(size_t)(bm * 64 + row) * E + col];
  }
  const short* bgp[2];
  int bldsb[2];
#pragma unroll
  for (int cc = 0; cc < 2; ++cc) {
    int seg = w * 2 + cc;
    int p = seg * 8 + (lane >> 3), kc = lane & 7;
    int l = kc ^ (p & 7);
    int row = 2 * p + (l >> 2), col = (l & 3) * 8;
    bldsb[cc] = seg * 512;
    bgp[cc] = &Bw[(size_t)(bn * 128 + row) * E + col];
  }

  f32x4 acc[2][4] = {};
  for (int k0 = 0; k0 < E; k0 += 32) {
    __syncthreads();
    gl_lds16(agp + k0, &as[aldsb]);
#pragma unroll
    for (int cc = 0; cc < 2; ++cc) gl_lds16(bgp[cc] + k0, &bs[bldsb[cc]]);
    __syncthreads();

    bf16x8 af[2], bf[4];
#pragma unroll
    for (int tt = 0; tt < 2; ++tt) {
      int ra = wm * 32 + tt * 16 + l15;
      int pa2 = ra >> 1, la = (ra & 1) * 4 + quad, ka = la ^ (pa2 & 7);
      af[tt] = *(bf16x8*)&as[pa2 * 64 + ka * 8];
    }
#pragma unroll
    for (int tt = 0; tt < 4; ++tt) {
      int rb = wn * 64 + tt * 16 + l15;
      int pb2 = rb >> 1, lb = (rb & 1) * 4 + quad, kb2 = lb ^ (pb2 & 7);
      bf[tt] = *(bf16x8*)&bs[pb2 * 64 + kb2 * 8];
    }
#pragma unroll
    for (int mt = 0; mt < 2; ++mt)
#pragma unroll
      for (int nt = 0; nt < 4; ++nt)
        acc[mt][nt] = __builtin_amdgcn_mfma_f32_16x16x32_bf16(
            af[mt], bf[nt], acc[mt][nt], 0, 0, 0);
  }

#pragma unroll
  for (int mt = 0; mt < 2; ++mt)
#pragma unroll
    for (int nt = 0; nt < 4; ++nt)
#pragma unroll
      for (int rr = 0; rr < 4; ++rr) {
        int row = bm * 64 + wm * 32 + mt * 16 + quad * 4 + rr;
        int col = bn * 128 + wn * 64 + nt * 16 + l15;
        float v = acc[mt][nt][rr] + bias[col];
        if (MODE == 0) {
          int n = row >> 11, s = row & 2047, h = col >> 6, d = col & 63;
          ((short*)outp)[(((size_t)(n * H + h) * D) + d) * S + s] =
              f2bf_rne(v);
        } else {
          ((float*)outp)[(size_t)row * E + col] = v;
        }
      }
}

// ---------------------------------------------------------------------------
// Flash attention (unchanged from R7): grid (16,32), XCD-pinned heads,
// S^T MFMA trick + fixed-base exp2 softmax + packed b64 P-writes.
// ---------------------------------------------------------------------------
__global__ __launch_bounds__(256) void attn_kernel(const short* __restrict__ q,
                                                   const short* __restrict__ k,
                                                   const short* __restrict__ vt,
                                                   short* __restrict__ ctx) {
  __shared__ __align__(16) short ks[128 * 72];      // 128 keys x 64 d
  __shared__ __align__(16) short vs[64 * 136];      // 64 d x 128 keys (V^T)
  __shared__ __align__(16) short ps[4 * 32 * 72];   // per-wave P 32 x 64

  const int tid = threadIdx.x;
  const int lane = tid & 63, wv = tid >> 6;
  const int l15 = lane & 15, quad = lane >> 4;

  const int bid = blockIdx.y * gridDim.x + blockIdx.x;  // 0..511
  const int c = bid & 7, r = bid >> 3;
  const int qt = r & 15;
  const int hz = c * 4 + (r >> 4);  // 0..31
  const int hh = hz & 15, nn = hz >> 4;

  const int nh = nn * H + hh;
  const size_t base = (size_t)nh * S * D;
  const int q0 = qt * 128 + wv * 32;
  const int pb = wv * 32 * 72;

  bf16x8 qf[2][2];
#pragma unroll
  for (int mt = 0; mt < 2; ++mt)
#pragma unroll
    for (int kk = 0; kk < 2; ++kk)
      qf[mt][kk] = *(const bf16x8*)&q[base + (size_t)(q0 + mt * 16 + l15) * D +
                                      kk * 32 + quad * 8];

  f32x4 o[2][4] = {};
  float lsum[2] = {0.f, 0.f};

  bf16x8 pk[4], pv[4];
  auto loadKV = [&](int j0) {
#pragma unroll
    for (int cc = 0; cc < 4; ++cc) {
      int ch = cc * 256 + tid;
      int kr = ch >> 3, kc = (ch & 7) * 8;   // 128 x 64
      pk[cc] = *(const bf16x8*)&k[base + (size_t)(j0 + kr) * D + kc];
      int vr = ch >> 4, vc = (ch & 15) * 8;  // 64 x 128
      pv[cc] = *(const bf16x8*)&vt[base + (size_t)vr * S + j0 + vc];
    }
  };

  loadKV(0);
  for (int j0 = 0; j0 < S; j0 += 128) {
    __syncthreads();
#pragma unroll
    for (int cc = 0; cc < 4; ++cc) {
      int ch = cc * 256 + tid;
      int kr = ch >> 3, kc = (ch & 7) * 8;
      *(bf16x8*)&ks[kr * 72 + kc] = pk[cc];
      int vr = ch >> 4, vc = (ch & 15) * 8;
      *(bf16x8*)&vs[vr * 136 + vc] = pv[cc];
    }
    __syncthreads();
    if (j0 + 128 < S) loadKV(j0 + 128);

#pragma unroll
    for (int half = 0; half < 2; ++half) {
      f32x4 sc[4][2] = {};
#pragma unroll
      for (int kk = 0; kk < 2; ++kk)
#pragma unroll
        for (int kt = 0; kt < 4; ++kt) {
          bf16x8 kf = *(bf16x8*)&ks[(half * 64 + kt * 16 + l15) * 72 +
                                    kk * 32 + quad * 8];
#pragma unroll
          for (int mt = 0; mt < 2; ++mt)
            sc[kt][mt] = __builtin_amdgcn_mfma_f32_16x16x32_bf16(
                kf, qf[mt][kk], sc[kt][mt], 0, 0, 0);
        }

#pragma unroll
      for (int kt = 0; kt < 4; ++kt)
#pragma unroll
        for (int mt = 0; mt < 2; ++mt) {
          bf16x4 pq;
#pragma unroll
          for (int rr = 0; rr < 4; ++rr) {
            float p = fast_exp2(sc[kt][mt][rr]);
            lsum[mt] += p;
            pq[rr] = f2bf_rne(p);
          }
          *(bf16x4*)&ps[pb + (mt * 16 + l15) * 72 + kt * 16 + quad * 4] = pq;
        }

#pragma unroll
      for (int kk = 0; kk < 2; ++kk) {
        bf16x8 af[2];
#pragma unroll
        for (int mt = 0; mt < 2; ++mt)
          af[mt] =
              *(bf16x8*)&ps[pb + (mt * 16 + l15) * 72 + kk * 32 + quad * 8];
#pragma unroll
        for (int nd = 0; nd < 4; ++nd) {
          bf16x8 bfv = *(bf16x8*)&vs[(nd * 16 + l15) * 136 + half * 64 +
                                     kk * 32 + quad * 8];
#pragma unroll
          for (int mt = 0; mt < 2; ++mt)
            o[mt][nd] = __builtin_amdgcn_mfma_f32_16x16x32_bf16(
                af[mt], bfv, o[mt][nd], 0, 0, 0);
        }
      }
    }
  }

#pragma unroll
  for (int mt = 0; mt < 2; ++mt) {
    lsum[mt] += __shfl_xor(lsum[mt], 16);
    lsum[mt] += __shfl_xor(lsum[mt], 32);
  }

#pragma unroll
  for (int mt = 0; mt < 2; ++mt)
#pragma unroll
    for (int rr = 0; rr < 4; ++rr) {
      int src = (lane & 48) + ((lane >> 4) & 3) * 4 + rr;
      float lfull = __shfl(lsum[mt], src);
      float inv = 1.0f / lfull;
      int srow = q0 + mt * 16 + quad * 4 + rr;
#pragma unroll
      for (int nd = 0; nd < 4; ++nd) {
        int d = nd * 16 + l15;
        ctx[((size_t)(nn * S + srow)) * E + hh * D + d] =
            f2bf_rne(o[mt][nd][rr] * inv);
      }
    }
}

// ---------------------------------------------------------------------------
extern "C" void kernel_launch(void* const* d_in, const int* in_sizes, int n_in,
                              void* d_out, int out_size, void* d_ws,
                              size_t ws_size, hipStream_t stream) {
  const float* values  = (const float*)d_in[0];
  const float* keys    = (const float*)d_in[1];
  const float* queries = (const float*)d_in[2];
  const float* b_v = (const float*)d_in[4];
  const float* b_k = (const float*)d_in[6];
  const float* b_q = (const float*)d_in[8];
  const float* W_v = (const float*)d_in[3];
  const float* W_k = (const float*)d_in[5];
  const float* W_q = (const float*)d_in[7];
  const float* W_o = (const float*)d_in[9];
  const float* b_o = (const float*)d_in[10];

  const size_t X = (size_t)M * E;      // 4M elements
  const size_t W = (size_t)E * E;      // 1M elements

  // d_out (16 MB): qb [0..4M shorts) + qbf [4M..8M shorts); both dead
  // before out_gemm overwrites d_out with fp32.
  short* qb  = (short*)d_out;
  short* qbf = (short*)d_out + X;
  // d_ws (32 MB): kb, vtb, castbuf (kbf -> vbf -> ctx, sequential reuse),
  // then 4 bf16 weights.
  short* kb      = (short*)d_ws;       // [0 .. 4M)
  short* vtb     = kb + X;             // [4M .. 8M)
  short* castbuf = vtb + X;            // [8M .. 12M)
  short* wqb = castbuf + X;            // [12M .. 13M)
  short* wkb = wqb + W;                // [13M .. 14M)
  short* wvb = wkb + W;                // [14M .. 15M)
  short* wob = wvb + W;                // [15M .. 16M)
  short* kbf = castbuf;
  short* vbf = castbuf;
  short* ctx = castbuf;

  cast_a<<<dim3(2048, 6), 256, 0, stream>>>(queries, keys, W_q, W_k, W_v, W_o,
                                            qbf, kbf, wqb, wkb, wvb, wob);
  qk_gemm<<<512, 256, 0, stream>>>(qbf, kbf, wqb, wkb, b_q, b_k, qb, kb);
  cast_one<<<2048, 256, 0, stream>>>(values, vbf);
  gemm64<0><<<512, 256, 0, stream>>>(vbf, wvb, b_v, vtb);
  attn_kernel<<<dim3(16, 32), 256, 0, stream>>>(qb, kb, vtb, ctx);
  gemm64<1><<<512, 256, 0, stream>>>(ctx, wob, b_o, d_out);
}